// Round 12
// baseline (1051.268 us; speedup 1.0000x reference)
//
#include <hip/hip_runtime.h>
#include <stdint.h>
#include <math.h>

#define B_   4
#define T_   4096
#define BT_  16384
#define HID  2048
#define ED   256
#define HD   32
#define NH   8
#define K3   768    // packed split K (hi|hi|lo)
#define KW   6144   // packed split K for W2 = Wo@Wv (hi|hi|lo over 2048)
#define KSP  8      // K-split for W2 GEMM

typedef unsigned short u16;
typedef __attribute__((ext_vector_type(8))) short short8;
typedef __attribute__((ext_vector_type(4))) float f32x4;

typedef __attribute__((address_space(1))) void gvoid;
typedef __attribute__((address_space(3))) void lvoid;

__device__ __forceinline__ float bf2f(u16 h) {
    return __uint_as_float(((uint32_t)h) << 16);
}
__device__ __forceinline__ u16 f2bf(float f) {
    uint32_t u = __float_as_uint(f);
    u += 0x7FFFu + ((u >> 16) & 1u);   // round-to-nearest-even
    return (u16)(u >> 16);
}
__device__ __forceinline__ void gld_lds16(const void* g, void* l) {
    __builtin_amdgcn_global_load_lds((gvoid*)(uintptr_t)g, (lvoid*)(uintptr_t)l, 16, 0, 0);
}
__device__ __forceinline__ void BAR() {
    asm volatile("" ::: "memory");
    __builtin_amdgcn_s_barrier();
    asm volatile("" ::: "memory");
}

// ---- Wk -> packed [hi | lo | hi] rows of 768 (pairs with A3 = [hi | hi | lo]) ----
__global__ void k_cvt_wk3(const float* __restrict__ in, u16* __restrict__ out) {
    int i = blockIdx.x * 256 + threadIdx.x;   // over HID*ED
    int n = i >> 8, c = i & 255;
    float f = in[i];
    u16 h = f2bf(f);
    out[(size_t)n * K3 + c]       = h;
    out[(size_t)n * K3 + 256 + c] = f2bf(f - bf2f(h));
    out[(size_t)n * K3 + 512 + c] = h;
}

// ---- Wo (2048x2048 f32) -> WoP [2048][6144] = [hi | hi | lo] ----
__global__ void k_packWo(const float* __restrict__ wo, u16* __restrict__ wop) {
    int i = blockIdx.x * 256 + threadIdx.x;   // over 2048*2048
    int o = i >> 11, n = i & 2047;
    float f = wo[i];
    u16 h = f2bf(f);
    wop[(size_t)o * KW + n]        = h;
    wop[(size_t)o * KW + 2048 + n] = h;
    wop[(size_t)o * KW + 4096 + n] = f2bf(f - bf2f(h));
}

// ---- Wv (2048x256 f32, row n col c) -> WvP [256][6144] = [hi | lo | hi] (transposed) ----
__global__ void k_packWv(const float* __restrict__ wv, u16* __restrict__ wvp) {
    int i = blockIdx.x * 256 + threadIdx.x;   // over 2048*256
    int n = i >> 8, c = i & 255;
    float f = wv[i];
    u16 h = f2bf(f);
    wvp[(size_t)c * KW + n]        = h;
    wvp[(size_t)c * KW + 2048 + n] = f2bf(f - bf2f(h));
    wvp[(size_t)c * KW + 4096 + n] = h;
}

// ---- reduce 8 K-split partials -> W2 f32 -> W23 [2048][768] = [hi | lo | hi] ----
__global__ void k_w2pack(const float* __restrict__ part, u16* __restrict__ w23) {
    int i = blockIdx.x * 256 + threadIdx.x;   // over 2048*256
    int o = i >> 8, c = i & 255;
    float s = 0.f;
#pragma unroll
    for (int k = 0; k < KSP; ++k) s += part[(size_t)k * HID * ED + i];
    u16 h = f2bf(s);
    w23[(size_t)o * K3 + c]       = h;
    w23[(size_t)o * K3 + 256 + c] = f2bf(s - bf2f(h));
    w23[(size_t)o * K3 + 512 + c] = h;
}

// ---------------- hash-embedding gather (f32) ----------------
__global__ void k_gather(const int* __restrict__ hashes, const int* __restrict__ offs,
                         const float* __restrict__ tab, float* __restrict__ E) {
    const int bt = blockIdx.x;
    const int tid = threadIdx.x;          // 256 = 8 heads x 32 dims
    const int head = tid >> 5, d = tid & 31;
    const int row = hashes[bt * NH + head] + offs[head];
    E[(size_t)bt * ED + tid] = tab[(size_t)row * HD + d];
}

// ---- conv + LN + silu + residual; writes A3 row = [e_hi | e_hi | e_lo] (768) ----
__global__ void k_conv(const float* __restrict__ E, const float* __restrict__ w,
                       const float* __restrict__ lng, const float* __restrict__ lnb,
                       u16* __restrict__ a3) {
    const int bt = blockIdx.x;
    const int b = bt >> 12;               // T_ = 4096
    const int t = bt & 4095;
    const int ch = threadIdx.x;           // 256
    float c = 0.f;
#pragma unroll
    for (int k = 0; k < 4; ++k) {
        int tt = t - 9 + 3 * k;           // taps at t-9, t-6, t-3, t
        if (tt >= 0)
            c += w[ch * 4 + k] * E[((size_t)(b * T_ + tt)) * ED + ch];
    }
    float s = c, s2 = c * c;
#pragma unroll
    for (int o = 32; o; o >>= 1) { s += __shfl_xor(s, o); s2 += __shfl_xor(s2, o); }
    __shared__ float red[8];
    const int wid = ch >> 6, lane = ch & 63;
    if (!lane) { red[wid] = s; red[4 + wid] = s2; }
    __syncthreads();
    s  = red[0] + red[1] + red[2] + red[3];
    s2 = red[4] + red[5] + red[6] + red[7];
    const float mean = s * (1.f / 256.f);
    const float var  = s2 * (1.f / 256.f) - mean * mean;
    float ln = (c - mean) * rsqrtf(var + 1e-5f) * lng[ch] + lnb[ch];
    float si = ln / (1.f + expf(-ln));    // silu
    float ev = E[(size_t)bt * ED + ch] + si;
    u16 h = f2bf(ev);
    a3[(size_t)bt * K3 + ch]       = h;
    a3[(size_t)bt * K3 + 256 + ch] = h;
    a3[(size_t)bt * K3 + 512 + ch] = f2bf(ev - bf2f(h));
}

// ---------------- per-row x stats: mu, rsqrt(var+eps) ----------------
__global__ void k_xstat(const float* __restrict__ x, float* __restrict__ xs) {
    const int m = blockIdx.x;
    const int tid = threadIdx.x;          // 256 thr, 2 float4 each
    const f32x4* xr = (const f32x4*)(x + (size_t)m * HID);
    float sx = 0.f, sx2 = 0.f;
#pragma unroll
    for (int i = 0; i < 2; ++i) {
        f32x4 xv = xr[tid + i * 256];
#pragma unroll
        for (int c = 0; c < 4; ++c) { sx += xv[c]; sx2 += xv[c] * xv[c]; }
    }
#pragma unroll
    for (int o = 32; o; o >>= 1) { sx += __shfl_xor(sx, o); sx2 += __shfl_xor(sx2, o); }
    __shared__ float red[8];
    const int wid = tid >> 6, lane = tid & 63;
    if (!lane) { red[wid] = sx; red[4 + wid] = sx2; }
    __syncthreads();
    if (tid == 0) {
        sx  = red[0] + red[1] + red[2] + red[3];
        sx2 = red[4] + red[5] + red[6] + red[7];
        const float inv = 1.f / (float)HID;
        const float mu = sx * inv, var = sx2 * inv - mu * mu;
        xs[m * 2]     = mu;
        xs[m * 2 + 1] = rsqrtf(var + 1e-5f);
    }
}

// ---------------- finalize gamma from 8 partial slices ----------------
// dot = rk*(T1 - mu_k*T2) + T3 ; partial[m][nb][5] = {S1,S2,T1,T2,T3}
__global__ void k_gamma2(const float* __restrict__ partial, float* __restrict__ gamma) {
    const int m = blockIdx.x * 256 + threadIdx.x;
    float s[5] = {0.f, 0.f, 0.f, 0.f, 0.f};
    const float* p = partial + (size_t)m * 40;
#pragma unroll
    for (int nb = 0; nb < 8; ++nb)
#pragma unroll
        for (int v = 0; v < 5; ++v) s[v] += p[nb * 5 + v];
    const float inv = 1.f / (float)HID;
    const float mu = s[0] * inv, var = s[1] * inv - mu * mu;
    const float rk = rsqrtf(var + 1e-5f);
    const float dot = rk * (s[2] - mu * s[3]) + s[4];
    const float gd = dot * 0.022097086912079608f;   // 1/sqrt(2048)
    const float sg = (gd > 0.f) ? 1.f : ((gd < 0.f) ? -1.f : 0.f);
    const float sv = sqrtf(fmaxf(fabsf(gd), 1e-6f)) * sg;
    gamma[m] = 1.f / (1.f + expf(-sv));
}

// ============ 256x256 / BK=32 bf16 MFMA GEMM — 64 KB LDS, 2 blocks/CU ============
// C[m,n] = sum_k A[m,k]*B[n,k]; A MxK (lda), B NxK (ldb), bf16.
// 512 thr = 8 waves (2M x 4N); per-wave out 128x64. LDS 64 KiB dynamic:
// A dbuf [0,32K), B dbuf [32K,64K); each buf = 256x32 bf16 (16 KB) stored as
// [128 phys rows][128 B] (2 matrix rows per phys row) with slot3 XOR-swizzle
// slot3 ^= physrow&7 applied on BOTH stage-source index and ds_read (involution):
//   byte(r,ks) = (r>>1)*128 + ((((r&1)<<2)|ks) ^ ((r>>1)&7))*16
// Read pattern is exactly 2-way bank-aliased (free, m136). Per-lane offset
// reduces to constant loff: row = C+l15 (C mult of 16) => (r>>1)&7 = l15>>1.
// r12: BK 64->32 halves LDS so TWO blocks/CU are resident (r11 had 1): the
// co-resident block's K-loop hides prologue/epilogue/barrier stalls (m114
// implicit overlap); all 512 blocks fit in one dispatch wave (no tail).
// Schedule (r5-proven, 2 barriers/K-tile): reads+4 MMQs | BAR | STAGE(t+2)
// (4 loads) vmcnt(4) drains t+1 | BAR. Never vmcnt(0) in steady state.
// GRID=0: 2D XCD chunking (grid 64x8 tiles). GRID=1: row-major + K-split
// via blockIdx.y. EPI: 0 = f32 K-split slab; 2 = fused key->gamma partials;
// 3 = f32 store with rowscale.
template <int EPI, int GRID>
__global__ __launch_bounds__(512, 4)
void gemm8(const u16* __restrict__ A, int lda, const u16* __restrict__ Bm, int ldb,
           const float* __restrict__ rowscale, void* __restrict__ Cout,
           int M, int N, int K,
           const float* __restrict__ xq, const float* __restrict__ xs,
           const float* __restrict__ gq, const float* __restrict__ bq,
           const float* __restrict__ gk, const float* __restrict__ bk,
           float* __restrict__ partial) {
    extern __shared__ char smem[];
    const int tid = threadIdx.x, wid = tid >> 6, lane = tid & 63;
    const int l15 = lane & 15, lhi = lane >> 4;
    const int wr = wid >> 2, wc = wid & 3;

    const int id = blockIdx.x;
    int mblk, nblk;
    if (GRID == 0) {
        const int xcd = id & 7, loc = id >> 3;
        mblk = ((xcd << 3) + (loc & 7)) << 8;
        nblk = (loc >> 3) << 8;
    } else {
        const int tiles_m = M >> 8;
        mblk = (id % tiles_m) << 8;
        nblk = (id / tiles_m) << 8;
        const size_t koff = (size_t)blockIdx.y * K;
        A  += koff;
        Bm += koff;
    }

    f32x4 acc[8][4];
#pragma unroll
    for (int i = 0; i < 8; ++i)
#pragma unroll
        for (int j = 0; j < 4; ++j) acc[i][j] = f32x4{0.f, 0.f, 0.f, 0.f};

    // ---- staging: thread (wid,lane,round r) -> linear LDS o = r*8192 + wid*1024 + lane*16
    // physrow = o>>7 = r*64 + wid*8 + (lane>>3); physrow&7 = lane>>3.
    // source element (pre-swizzled): slot3 = (lane&7)^(lane>>3);
    // matrix row = 2*physrow + (slot3>>2); k-col(u16) = (slot3&3)*8.
    const int slot3 = (lane & 7) ^ (lane >> 3);
    const int kcol  = (slot3 & 3) * 8;
    const u16* aSrc[2];
    const u16* bSrc[2];
#pragma unroll
    for (int r = 0; r < 2; ++r) {
        const int mrow = 2 * (r * 64 + wid * 8 + (lane >> 3)) + (slot3 >> 2);
        aSrc[r] = A  + (size_t)(mblk + mrow) * lda + kcol;
        bSrc[r] = Bm + (size_t)(nblk + mrow) * ldb + kcol;
    }
    const int wb = wid * 1024 + (lane << 4);   // thread's LDS byte (dest is base+lane*16)
    const int wbase = wid * 1024;              // wave-uniform base

    // ---- read offsets: byte = bufbase + C*64 + loff, C = row-block const (mult of 16)
    const int loff = (l15 >> 1) * 128 + (((((l15 & 1) << 2) | lhi)) ^ (l15 >> 1)) * 16;

    short8 ar[4], br[2][2];

#define STAGE_TILE(tt) do { const int q_ = (tt) & 1; const int kk_ = (tt) << 5;      \
        char* da_ = smem + q_ * 16384 + wbase;                                       \
        char* db_ = smem + 32768 + q_ * 16384 + wbase;                               \
        gld_lds16(aSrc[0] + kk_, da_);  gld_lds16(aSrc[1] + kk_, da_ + 8192);        \
        gld_lds16(bSrc[0] + kk_, db_);  gld_lds16(bSrc[1] + kk_, db_ + 8192);        \
    } while (0)
#define LDA_SUB(mh, p) do {                                                          \
        const char* ab_ = smem + (p) * 16384 + ((mh) * 128 + wr * 64) * 64 + loff;   \
        _Pragma("unroll") for (int fm = 0; fm < 4; ++fm)                             \
            ar[fm] = *(const short8*)(ab_ + fm * 1024); } while (0)
#define LDB_SUB(nh, p) do {                                                          \
        const char* bb_ = smem + 32768 + (p) * 16384                                 \
                          + ((nh) * 128 + wc * 32) * 64 + loff;                      \
        _Pragma("unroll") for (int fn = 0; fn < 2; ++fn)                             \
            br[nh][fn] = *(const short8*)(bb_ + fn * 1024); } while (0)
#define MMQ(mh, nh) do { __builtin_amdgcn_s_setprio(1);                              \
        _Pragma("unroll") for (int fm = 0; fm < 4; ++fm)                             \
        _Pragma("unroll") for (int fn = 0; fn < 2; ++fn)                             \
            acc[(mh) * 4 + fm][(nh) * 2 + fn] = __builtin_amdgcn_mfma_f32_16x16x32_bf16( \
                ar[fm], br[nh][fn], acc[(mh) * 4 + fm][(nh) * 2 + fn], 0, 0, 0);     \
        __builtin_amdgcn_s_setprio(0); } while (0)

    // prologue: tiles 0,1 staged (8 loads); drain tile 0 (oldest 4)
    STAGE_TILE(0);
    STAGE_TILE(1);
    asm volatile("s_waitcnt vmcnt(4)" ::: "memory");
    BAR();

    const int nk = K >> 5;
    for (int t = 0; t < nk; ++t) {
        const int p = t & 1;
        LDA_SUB(0, p); LDB_SUB(0, p);
        MMQ(0, 0);
        LDB_SUB(1, p);
        MMQ(0, 1);
        LDA_SUB(1, p);
        MMQ(1, 0);
        MMQ(1, 1);
        BAR();   // all waves done reading buf p (operand lgkm waits guarantee per-wave)
        if (t + 2 < nk) {
            STAGE_TILE(t + 2);   // overwrite buf p
            asm volatile("s_waitcnt vmcnt(4)" ::: "memory");   // drain tile t+1
        } else {
            asm volatile("s_waitcnt vmcnt(0)" ::: "memory");   // tail drain
        }
        BAR();   // publish tile t+1
    }
#undef STAGE_TILE
#undef LDA_SUB
#undef LDB_SUB
#undef MMQ

    if (EPI == 2) {
        // ---- fused key->gamma partial reduction (key stays in registers) ----
        float gqv[4], bqv[4], gkv[4], bkv[4];
#pragma unroll
        for (int nj = 0; nj < 4; ++nj) {
            const int n = nblk + (nj >> 1) * 128 + wc * 32 + (nj & 1) * 16 + l15;
            gqv[nj] = gq[n]; bqv[nj] = bq[n]; gkv[nj] = gk[n]; bkv[nj] = bk[n];
        }
        float* red = (float*)smem;           // [256 rows][4 wc][5] = 20 KB
#pragma unroll
        for (int mi = 0; mi < 8; ++mi) {
#pragma unroll
            for (int rr = 0; rr < 4; ++rr) {
                const int rloc = (mi >> 2) * 128 + wr * 64 + (mi & 3) * 16 + lhi * 4 + rr;
                const int m = mblk + rloc;
                const float mu = xs[m * 2], rx = xs[m * 2 + 1];
                float s1 = 0.f, s2 = 0.f, t1 = 0.f, t2 = 0.f, t3 = 0.f;
#pragma unroll
                for (int nj = 0; nj < 4; ++nj) {
                    const float kv = acc[mi][nj][rr];
                    const int n = nblk + (nj >> 1) * 128 + wc * 32 + (nj & 1) * 16 + l15;
                    const float xv = xq[(size_t)m * N + n];
                    const float q  = (xv - mu) * rx * gqv[nj] + bqv[nj];
                    const float qg = q * gkv[nj];
                    s1 += kv; s2 += kv * kv;
                    t1 += qg * kv; t2 += qg; t3 += q * bkv[nj];
                }
#pragma unroll
                for (int o = 1; o < 16; o <<= 1) {
                    s1 += __shfl_xor(s1, o); s2 += __shfl_xor(s2, o);
                    t1 += __shfl_xor(t1, o); t2 += __shfl_xor(t2, o);
                    t3 += __shfl_xor(t3, o);
                }
                if (l15 == 0) {
                    float* d = red + ((size_t)rloc * 4 + wc) * 5;
                    d[0] = s1; d[1] = s2; d[2] = t1; d[3] = t2; d[4] = t3;
                }
            }
        }
        BAR();
        const int nb = nblk >> 8;
        for (int e = tid; e < 1280; e += 512) {
            const int row = e / 5, v = e - row * 5;
            const float s = red[((size_t)row * 4 + 0) * 5 + v] + red[((size_t)row * 4 + 1) * 5 + v]
                          + red[((size_t)row * 4 + 2) * 5 + v] + red[((size_t)row * 4 + 3) * 5 + v];
            partial[((size_t)(mblk + row) * 8 + nb) * 5 + v] = s;
        }
    } else {
        // direct fragment epilogue: D row=(lane>>4)*4+r, col=lane&15
        float* Cf = (float*)Cout;
        if (EPI == 0 && GRID == 1) Cf += (size_t)blockIdx.y * M * N;   // K-split slab
#pragma unroll
        for (int mi = 0; mi < 8; ++mi) {
#pragma unroll
            for (int rr = 0; rr < 4; ++rr) {
                const int m = mblk + (mi >> 2) * 128 + wr * 64 + (mi & 3) * 16 + lhi * 4 + rr;
                const float sc = (EPI == 3) ? rowscale[m] : 1.0f;
#pragma unroll
                for (int nj = 0; nj < 4; ++nj) {
                    const int n = nblk + (nj >> 1) * 128 + wc * 32 + (nj & 1) * 16 + l15;
                    Cf[(size_t)m * N + n] = acc[mi][nj][rr] * sc;
                }
            }
        }
    }
}

extern "C" void kernel_launch(void* const* d_in, const int* in_sizes, int n_in,
                              void* d_out, int out_size, void* d_ws, size_t ws_size,
                              hipStream_t stream) {
    const float* x      = (const float*)d_in[0];
    const int*   hashes = (const int*)d_in[1];
    const int*   offs   = (const int*)d_in[2];
    const float* emb    = (const float*)d_in[3];
    const float* conv_w = (const float*)d_in[4];
    const float* lncg   = (const float*)d_in[5];
    const float* lncb   = (const float*)d_in[6];
    const float* Wk     = (const float*)d_in[7];
    const float* Wv     = (const float*)d_in[8];
    const float* Wo     = (const float*)d_in[9];
    const float* lnkg   = (const float*)d_in[10];
    const float* lnkb   = (const float*)d_in[11];
    const float* lnqg   = (const float*)d_in[12];
    const float* lnqb   = (const float*)d_in[13];

    // ws (~80 MB). E (16.8MB, dead after k_conv) aliases W2part. key/value never
    // materialized: out = gamma * (e @ (Wo@Wv)^T).
    char* p = (char*)d_ws;
    float* E      = (float*)p;
    float* W2part = (float*)p;  p += (size_t)KSP * HID * ED * 4;  // 16.8 MB
    u16*   A3     = (u16*)p;    p += (size_t)BT_ * K3 * 2;        // 25.2 MB
    u16*   Wk3    = (u16*)p;    p += (size_t)HID * K3 * 2;        // 3.1 MB
    u16*   WoP    = (u16*)p;    p += (size_t)HID * KW * 2;        // 25.2 MB
    u16*   WvP    = (u16*)p;    p += (size_t)ED * KW * 2;         // 3.1 MB
    u16*   W23    = (u16*)p;    p += (size_t)HID * K3 * 2;        // 3.1 MB
    float* xs     = (float*)p;  p += (size_t)BT_ * 2 * 4;         // 128 KB
    float* part   = (float*)p;  p += (size_t)BT_ * 8 * 5 * 4;     // 2.6 MB
    float* gamma  = (float*)p;  p += (size_t)BT_ * 4;             // 64 KB

    hipFuncSetAttribute((const void*)gemm8<0, 1>,
                        hipFuncAttributeMaxDynamicSharedMemorySize, 65536);
    hipFuncSetAttribute((const void*)gemm8<2, 0>,
                        hipFuncAttributeMaxDynamicSharedMemorySize, 65536);
    hipFuncSetAttribute((const void*)gemm8<3, 0>,
                        hipFuncAttributeMaxDynamicSharedMemorySize, 65536);

    k_cvt_wk3<<<(HID * ED) / 256, 256, 0, stream>>>(Wk, Wk3);
    k_packWo<<<(HID * HID) / 256, 256, 0, stream>>>(Wo, WoP);
    k_packWv<<<(HID * ED) / 256, 256, 0, stream>>>(Wv, WvP);
    k_gather<<<BT_, 256, 0, stream>>>(hashes, offs, emb, E);
    k_conv<<<BT_, 256, 0, stream>>>(E, conv_w, lncg, lncb, A3);
    k_xstat<<<BT_, 256, 0, stream>>>(x, xs);

    // W2 = Wo @ Wv split-precision, K-split 8 x 768 -> f32 slabs (over dead E)
    gemm8<0, 1><<<dim3(HID / 256, KSP), 512, 65536, stream>>>(
        WoP, KW, WvP, KW, nullptr, W2part, HID, ED, KW / KSP,
        nullptr, nullptr, nullptr, nullptr, nullptr, nullptr, nullptr);
    k_w2pack<<<(HID * ED) / 256, 256, 0, stream>>>(W2part, W23);

    const dim3 grid((BT_ / 256) * (HID / 256));   // 512 = 64x8 tiles, 2/CU resident
    // key partials: A3 @ Wk3^T (K=768), gamma reduction fused in epilogue
    gemm8<2, 0><<<grid, 512, 65536, stream>>>(
        A3, K3, Wk3, K3, nullptr, nullptr, BT_, HID, K3,
        x, xs, lnqg, lnqb, lnkg, lnkb, part);
    k_gamma2<<<BT_ / 256, 256, 0, stream>>>(part, gamma);
    // out = gamma * (A3 @ W23^T)  (K=768) -> d_out f32
    gemm8<3, 0><<<grid, 512, 65536, stream>>>(
        A3, K3, W23, K3, gamma, d_out, BT_, HID, K3,
        nullptr, nullptr, nullptr, nullptr, nullptr, nullptr, nullptr);
}

// Round 13
// 295.120 us; speedup vs baseline: 3.5622x; 3.5622x over previous
//
#include <hip/hip_runtime.h>
#include <stdint.h>
#include <math.h>

#define B_   4
#define T_   4096
#define BT_  16384
#define HID  2048
#define ED   256
#define HD   32
#define NH   8
#define K3   768    // packed split K (hi|hi|lo)
#define KW   6144   // packed split K for W2 = Wo@Wv (hi|hi|lo over 2048)
#define KSP  8      // K-split for W2 GEMM
#define NB   16     // n-slabs for gamma partials (2048/128)

typedef unsigned short u16;
typedef __attribute__((ext_vector_type(8))) short short8;
typedef __attribute__((ext_vector_type(4))) float f32x4;

typedef __attribute__((address_space(1))) void gvoid;
typedef __attribute__((address_space(3))) void lvoid;

__device__ __forceinline__ float bf2f(u16 h) {
    return __uint_as_float(((uint32_t)h) << 16);
}
__device__ __forceinline__ u16 f2bf(float f) {
    uint32_t u = __float_as_uint(f);
    u += 0x7FFFu + ((u >> 16) & 1u);   // round-to-nearest-even
    return (u16)(u >> 16);
}
__device__ __forceinline__ void gld_lds16(const void* g, void* l) {
    __builtin_amdgcn_global_load_lds((gvoid*)(uintptr_t)g, (lvoid*)(uintptr_t)l, 16, 0, 0);
}
__device__ __forceinline__ void BAR() {
    asm volatile("" ::: "memory");
    __builtin_amdgcn_s_barrier();
    asm volatile("" ::: "memory");
}

// ---- Wk -> packed [hi | lo | hi] rows of 768 (pairs with A3 = [hi | hi | lo]) ----
__global__ void k_cvt_wk3(const float* __restrict__ in, u16* __restrict__ out) {
    int i = blockIdx.x * 256 + threadIdx.x;   // over HID*ED
    int n = i >> 8, c = i & 255;
    float f = in[i];
    u16 h = f2bf(f);
    out[(size_t)n * K3 + c]       = h;
    out[(size_t)n * K3 + 256 + c] = f2bf(f - bf2f(h));
    out[(size_t)n * K3 + 512 + c] = h;
}

// ---- Wo (2048x2048 f32) -> WoP [2048][6144] = [hi | hi | lo] ----
__global__ void k_packWo(const float* __restrict__ wo, u16* __restrict__ wop) {
    int i = blockIdx.x * 256 + threadIdx.x;   // over 2048*2048
    int o = i >> 11, n = i & 2047;
    float f = wo[i];
    u16 h = f2bf(f);
    wop[(size_t)o * KW + n]        = h;
    wop[(size_t)o * KW + 2048 + n] = h;
    wop[(size_t)o * KW + 4096 + n] = f2bf(f - bf2f(h));
}

// ---- Wv (2048x256 f32, row n col c) -> WvP [256][6144] = [hi | lo | hi] (transposed) ----
__global__ void k_packWv(const float* __restrict__ wv, u16* __restrict__ wvp) {
    int i = blockIdx.x * 256 + threadIdx.x;   // over 2048*256
    int n = i >> 8, c = i & 255;
    float f = wv[i];
    u16 h = f2bf(f);
    wvp[(size_t)c * KW + n]        = h;
    wvp[(size_t)c * KW + 2048 + n] = f2bf(f - bf2f(h));
    wvp[(size_t)c * KW + 4096 + n] = h;
}

// ---- reduce 8 K-split partials -> W2 f32 -> W23 [2048][768] = [hi | lo | hi] ----
__global__ void k_w2pack(const float* __restrict__ part, u16* __restrict__ w23) {
    int i = blockIdx.x * 256 + threadIdx.x;   // over 2048*256
    int o = i >> 8, c = i & 255;
    float s = 0.f;
#pragma unroll
    for (int k = 0; k < KSP; ++k) s += part[(size_t)k * HID * ED + i];
    u16 h = f2bf(s);
    w23[(size_t)o * K3 + c]       = h;
    w23[(size_t)o * K3 + 256 + c] = f2bf(s - bf2f(h));
    w23[(size_t)o * K3 + 512 + c] = h;
}

// ---------------- hash-embedding gather (f32) ----------------
__global__ void k_gather(const int* __restrict__ hashes, const int* __restrict__ offs,
                         const float* __restrict__ tab, float* __restrict__ E) {
    const int bt = blockIdx.x;
    const int tid = threadIdx.x;          // 256 = 8 heads x 32 dims
    const int head = tid >> 5, d = tid & 31;
    const int row = hashes[bt * NH + head] + offs[head];
    E[(size_t)bt * ED + tid] = tab[(size_t)row * HD + d];
}

// ---- conv + LN + silu + residual; writes A3 row = [e_hi | e_hi | e_lo] (768) ----
__global__ void k_conv(const float* __restrict__ E, const float* __restrict__ w,
                       const float* __restrict__ lng, const float* __restrict__ lnb,
                       u16* __restrict__ a3) {
    const int bt = blockIdx.x;
    const int b = bt >> 12;               // T_ = 4096
    const int t = bt & 4095;
    const int ch = threadIdx.x;           // 256
    float c = 0.f;
#pragma unroll
    for (int k = 0; k < 4; ++k) {
        int tt = t - 9 + 3 * k;           // taps at t-9, t-6, t-3, t
        if (tt >= 0)
            c += w[ch * 4 + k] * E[((size_t)(b * T_ + tt)) * ED + ch];
    }
    float s = c, s2 = c * c;
#pragma unroll
    for (int o = 32; o; o >>= 1) { s += __shfl_xor(s, o); s2 += __shfl_xor(s2, o); }
    __shared__ float red[8];
    const int wid = ch >> 6, lane = ch & 63;
    if (!lane) { red[wid] = s; red[4 + wid] = s2; }
    __syncthreads();
    s  = red[0] + red[1] + red[2] + red[3];
    s2 = red[4] + red[5] + red[6] + red[7];
    const float mean = s * (1.f / 256.f);
    const float var  = s2 * (1.f / 256.f) - mean * mean;
    float ln = (c - mean) * rsqrtf(var + 1e-5f) * lng[ch] + lnb[ch];
    float si = ln / (1.f + expf(-ln));    // silu
    float ev = E[(size_t)bt * ED + ch] + si;
    u16 h = f2bf(ev);
    a3[(size_t)bt * K3 + ch]       = h;
    a3[(size_t)bt * K3 + 256 + ch] = h;
    a3[(size_t)bt * K3 + 512 + ch] = f2bf(ev - bf2f(h));
}

// ---------------- per-row x stats: mu, rsqrt(var+eps) ----------------
__global__ void k_xstat(const float* __restrict__ x, float* __restrict__ xs) {
    const int m = blockIdx.x;
    const int tid = threadIdx.x;          // 256 thr, 2 float4 each
    const f32x4* xr = (const f32x4*)(x + (size_t)m * HID);
    float sx = 0.f, sx2 = 0.f;
#pragma unroll
    for (int i = 0; i < 2; ++i) {
        f32x4 xv = xr[tid + i * 256];
#pragma unroll
        for (int c = 0; c < 4; ++c) { sx += xv[c]; sx2 += xv[c] * xv[c]; }
    }
#pragma unroll
    for (int o = 32; o; o >>= 1) { sx += __shfl_xor(sx, o); sx2 += __shfl_xor(sx2, o); }
    __shared__ float red[8];
    const int wid = tid >> 6, lane = tid & 63;
    if (!lane) { red[wid] = sx; red[4 + wid] = sx2; }
    __syncthreads();
    if (tid == 0) {
        sx  = red[0] + red[1] + red[2] + red[3];
        sx2 = red[4] + red[5] + red[6] + red[7];
        const float inv = 1.f / (float)HID;
        const float mu = sx * inv, var = sx2 * inv - mu * mu;
        xs[m * 2]     = mu;
        xs[m * 2 + 1] = rsqrtf(var + 1e-5f);
    }
}

// ---------------- finalize gamma from NB partial slices ----------------
// dot = rk*(T1 - mu_k*T2) + T3 ; partial[m][nb][5] = {S1,S2,T1,T2,T3}
__global__ void k_gamma2(const float* __restrict__ partial, float* __restrict__ gamma) {
    const int m = blockIdx.x * 256 + threadIdx.x;
    float s[5] = {0.f, 0.f, 0.f, 0.f, 0.f};
    const float* p = partial + (size_t)m * (NB * 5);
#pragma unroll
    for (int nb = 0; nb < NB; ++nb)
#pragma unroll
        for (int v = 0; v < 5; ++v) s[v] += p[nb * 5 + v];
    const float inv = 1.f / (float)HID;
    const float mu = s[0] * inv, var = s[1] * inv - mu * mu;
    const float rk = rsqrtf(var + 1e-5f);
    const float dot = rk * (s[2] - mu * s[3]) + s[4];
    const float gd = dot * 0.022097086912079608f;   // 1/sqrt(2048)
    const float sg = (gd > 0.f) ? 1.f : ((gd < 0.f) ? -1.f : 0.f);
    const float sv = sqrtf(fmaxf(fabsf(gd), 1e-6f)) * sg;
    gamma[m] = 1.f / (1.f + expf(-sv));
}

// ============ 128x128 / BK=64 bf16 MFMA GEMM — 64 KB LDS, 2 blocks/CU ============
// C[m,n] = sum_k A[m,k]*B[n,k]; A MxK (lda), B NxK (ldb), bf16.
// 256 thr = 4 waves (2M x 2N); per-wave out 64x64 (acc = 64 f32 regs -> total
// VGPR ~180 <= 256 at 2 waves/SIMD: NO forced cap, no spill — r12's failure).
// LDS 64 KiB dynamic: A dbuf [0,32K), B dbuf [32K,64K); each buf = 128 rows x
// 128 B (BK=64), XOR-swizzle byte^=((row&7)<<4) on BOTH stage-source column
// and ds_read (involution; identical row geometry to the r11-proven layout).
// r13: 2 INDEPENDENT blocks/CU (64KB LDS, VGPR-safe) — co-resident block's
// K-loop hides the other's prologue/epilogue/barrier stalls (m114 overlap),
// which r11's 1-block/CU left exposed (EPI2 MfmaUtil 22% vs 42% at long K).
// Schedule (r5-proven, 2 barriers/K-tile): reads+MMQ | BAR | STAGE(t+2)
// (8 loads) + vmcnt(8) drains tile t+1 | BAR. Never vmcnt(0) in steady state.
// GRID=0: 2D XCD chunking (grid 128x16 tiles, id&7 = xcd owns 16x16 chunk).
// GRID=1: row-major + K-split via blockIdx.y (EPI0 -> f32 slab blockIdx.y).
// EPI: 0 = f32 K-split slab; 2 = fused key->gamma partials (key never
// materialized); 3 = f32 store with rowscale.
template <int EPI, int GRID>
__global__ __launch_bounds__(256, 2)
void gemm8(const u16* __restrict__ A, int lda, const u16* __restrict__ Bm, int ldb,
           const float* __restrict__ rowscale, void* __restrict__ Cout,
           int M, int N, int K,
           const float* __restrict__ xq, const float* __restrict__ xs,
           const float* __restrict__ gq, const float* __restrict__ bq,
           const float* __restrict__ gk, const float* __restrict__ bk,
           float* __restrict__ partial) {
    extern __shared__ char smem[];
    const int tid = threadIdx.x, wid = tid >> 6, lane = tid & 63;
    const int l15 = lane & 15, lhi = lane >> 4;
    const int wr = wid >> 1, wc = wid & 1;

    const int id = blockIdx.x;
    int mblk, nblk;
    if (GRID == 0) {
        // 2048 blocks: xcd = id&7 owns a 16(m) x 16(n) tile chunk
        const int xcd = id & 7, loc = id >> 3;
        mblk = ((xcd << 4) + (loc & 15)) << 7;
        nblk = (loc >> 4) << 7;
    } else {
        const int tiles_m = M >> 7;
        mblk = (id % tiles_m) << 7;
        nblk = (id / tiles_m) << 7;
        const size_t koff = (size_t)blockIdx.y * K;
        A  += koff;
        Bm += koff;
    }

    f32x4 acc[4][4];
#pragma unroll
    for (int i = 0; i < 4; ++i)
#pragma unroll
        for (int j = 0; j < 4; ++j) acc[i][j] = f32x4{0.f, 0.f, 0.f, 0.f};

    // staging: per matrix per tile 16KB = 4 rounds x 256 thr x 16B.
    // round r: LDS byte o = r*4096 + tid*16 -> row = r*32 + (tid>>3), slot = tid&7;
    // source col pre-swizzled (involution with the read-side XOR).
    const int srow = tid >> 3;
    const int scol = ((tid & 7) << 3) ^ ((srow & 7) << 3);
    const u16* aS[4];
    const u16* bS[4];
#pragma unroll
    for (int r = 0; r < 4; ++r) {
        aS[r] = A  + (size_t)(mblk + r * 32 + srow) * lda + scol;
        bS[r] = Bm + (size_t)(nblk + r * 32 + srow) * ldb + scol;
    }
    const int wb = wid * 1024;   // wave-uniform base within a round (lane*16 added by HW)

    const int koff0 = (lhi * 16) ^ ((l15 & 7) << 4);
    const int koff1 = (64 + lhi * 16) ^ ((l15 & 7) << 4);

    short8 ar[4][2], br[4][2];

#define STAGE_TILE(tt) do { const int q_ = (tt) & 1; const int kk_ = (tt) << 6;      \
        char* da_ = smem + q_ * 16384 + wb;                                          \
        char* db_ = smem + 32768 + q_ * 16384 + wb;                                  \
        gld_lds16(aS[0] + kk_, da_);          gld_lds16(aS[1] + kk_, da_ + 4096);    \
        gld_lds16(aS[2] + kk_, da_ + 8192);   gld_lds16(aS[3] + kk_, da_ + 12288);   \
        gld_lds16(bS[0] + kk_, db_);          gld_lds16(bS[1] + kk_, db_ + 4096);    \
        gld_lds16(bS[2] + kk_, db_ + 8192);   gld_lds16(bS[3] + kk_, db_ + 12288);   \
    } while (0)
#define LDA_ALL(p) do {                                                              \
        const char* ab_ = smem + (p) * 16384 + (wr * 64) * 128;                      \
        _Pragma("unroll") for (int fm = 0; fm < 4; ++fm) {                           \
            const char* rb_ = ab_ + (fm * 16 + l15) * 128;                           \
            ar[fm][0] = *(const short8*)(rb_ + koff0);                               \
            ar[fm][1] = *(const short8*)(rb_ + koff1); } } while (0)
#define LDB_ALL(p) do {                                                              \
        const char* bb_ = smem + 32768 + (p) * 16384 + (wc * 64) * 128;              \
        _Pragma("unroll") for (int fn = 0; fn < 4; ++fn) {                           \
            const char* rb_ = bb_ + (fn * 16 + l15) * 128;                           \
            br[fn][0] = *(const short8*)(rb_ + koff0);                               \
            br[fn][1] = *(const short8*)(rb_ + koff1); } } while (0)
#define MMQ_ALL() do { __builtin_amdgcn_s_setprio(1);                                \
        _Pragma("unroll") for (int fm = 0; fm < 4; ++fm)                             \
        _Pragma("unroll") for (int fn = 0; fn < 4; ++fn) {                           \
            acc[fm][fn] = __builtin_amdgcn_mfma_f32_16x16x32_bf16(                   \
                ar[fm][0], br[fn][0], acc[fm][fn], 0, 0, 0);                         \
            acc[fm][fn] = __builtin_amdgcn_mfma_f32_16x16x32_bf16(                   \
                ar[fm][1], br[fn][1], acc[fm][fn], 0, 0, 0); }                       \
        __builtin_amdgcn_s_setprio(0); } while (0)

    // prologue: tiles 0,1 staged (16 loads); drain tile 0 (oldest 8)
    STAGE_TILE(0);
    STAGE_TILE(1);
    asm volatile("s_waitcnt vmcnt(8)" ::: "memory");
    BAR();

    const int nk = K >> 6;
    for (int t = 0; t < nk; ++t) {
        const int p = t & 1;
        LDA_ALL(p); LDB_ALL(p);
        MMQ_ALL();
        BAR();   // all waves done reading buf p (operand lgkm waits guarantee per-wave)
        if (t + 2 < nk) {
            STAGE_TILE(t + 2);   // overwrite buf p
            asm volatile("s_waitcnt vmcnt(8)" ::: "memory");   // drain tile t+1
        } else {
            asm volatile("s_waitcnt vmcnt(0)" ::: "memory");   // tail drain
        }
        BAR();   // publish tile t+1
    }
#undef STAGE_TILE
#undef LDA_ALL
#undef LDB_ALL
#undef MMQ_ALL

    if (EPI == 2) {
        // ---- fused key->gamma partial reduction (key stays in registers) ----
        float gqv[4], bqv[4], gkv[4], bkv[4];
#pragma unroll
        for (int nj = 0; nj < 4; ++nj) {
            const int n = nblk + wc * 64 + nj * 16 + l15;
            gqv[nj] = gq[n]; bqv[nj] = bq[n]; gkv[nj] = gk[n]; bkv[nj] = bk[n];
        }
        float* red = (float*)smem;           // [128 rows][2 wc][5] = 5 KB
#pragma unroll
        for (int mi = 0; mi < 4; ++mi) {
#pragma unroll
            for (int rr = 0; rr < 4; ++rr) {
                const int rloc = wr * 64 + mi * 16 + lhi * 4 + rr;
                const int m = mblk + rloc;
                const float mu = xs[m * 2], rx = xs[m * 2 + 1];
                float s1 = 0.f, s2 = 0.f, t1 = 0.f, t2 = 0.f, t3 = 0.f;
#pragma unroll
                for (int nj = 0; nj < 4; ++nj) {
                    const float kv = acc[mi][nj][rr];
                    const int n = nblk + wc * 64 + nj * 16 + l15;
                    const float xv = xq[(size_t)m * N + n];
                    const float q  = (xv - mu) * rx * gqv[nj] + bqv[nj];
                    const float qg = q * gkv[nj];
                    s1 += kv; s2 += kv * kv;
                    t1 += qg * kv; t2 += qg; t3 += q * bkv[nj];
                }
#pragma unroll
                for (int o = 1; o < 16; o <<= 1) {
                    s1 += __shfl_xor(s1, o); s2 += __shfl_xor(s2, o);
                    t1 += __shfl_xor(t1, o); t2 += __shfl_xor(t2, o);
                    t3 += __shfl_xor(t3, o);
                }
                if (l15 == 0) {
                    float* d = red + ((size_t)rloc * 2 + wc) * 5;
                    d[0] = s1; d[1] = s2; d[2] = t1; d[3] = t2; d[4] = t3;
                }
            }
        }
        BAR();
        const int nb = nblk >> 7;
        for (int e = tid; e < 640; e += 256) {
            const int row = e / 5, v = e - row * 5;
            const float s = red[((size_t)row * 2 + 0) * 5 + v]
                          + red[((size_t)row * 2 + 1) * 5 + v];
            partial[((size_t)(mblk + row) * NB + nb) * 5 + v] = s;
        }
    } else {
        // direct fragment epilogue: D row=(lane>>4)*4+r, col=lane&15
        float* Cf = (float*)Cout;
        if (EPI == 0 && GRID == 1) Cf += (size_t)blockIdx.y * M * N;   // K-split slab
#pragma unroll
        for (int mi = 0; mi < 4; ++mi) {
#pragma unroll
            for (int rr = 0; rr < 4; ++rr) {
                const int m = mblk + wr * 64 + mi * 16 + lhi * 4 + rr;
                const float sc = (EPI == 3) ? rowscale[m] : 1.0f;
#pragma unroll
                for (int nj = 0; nj < 4; ++nj) {
                    const int n = nblk + wc * 64 + nj * 16 + l15;
                    Cf[(size_t)m * N + n] = acc[mi][nj][rr] * sc;
                }
            }
        }
    }
}

extern "C" void kernel_launch(void* const* d_in, const int* in_sizes, int n_in,
                              void* d_out, int out_size, void* d_ws, size_t ws_size,
                              hipStream_t stream) {
    const float* x      = (const float*)d_in[0];
    const int*   hashes = (const int*)d_in[1];
    const int*   offs   = (const int*)d_in[2];
    const float* emb    = (const float*)d_in[3];
    const float* conv_w = (const float*)d_in[4];
    const float* lncg   = (const float*)d_in[5];
    const float* lncb   = (const float*)d_in[6];
    const float* Wk     = (const float*)d_in[7];
    const float* Wv     = (const float*)d_in[8];
    const float* Wo     = (const float*)d_in[9];
    const float* lnkg   = (const float*)d_in[10];
    const float* lnkb   = (const float*)d_in[11];
    const float* lnqg   = (const float*)d_in[12];
    const float* lnqb   = (const float*)d_in[13];

    // ws (~85 MB). E (16.8MB, dead after k_conv) aliases W2part. key/value never
    // materialized: out = gamma * (e @ (Wo@Wv)^T).
    char* p = (char*)d_ws;
    float* E      = (float*)p;
    float* W2part = (float*)p;  p += (size_t)KSP * HID * ED * 4;  // 16.8 MB
    u16*   A3     = (u16*)p;    p += (size_t)BT_ * K3 * 2;        // 25.2 MB
    u16*   Wk3    = (u16*)p;    p += (size_t)HID * K3 * 2;        // 3.1 MB
    u16*   WoP    = (u16*)p;    p += (size_t)HID * KW * 2;        // 25.2 MB
    u16*   WvP    = (u16*)p;    p += (size_t)ED * KW * 2;         // 3.1 MB
    u16*   W23    = (u16*)p;    p += (size_t)HID * K3 * 2;        // 3.1 MB
    float* xs     = (float*)p;  p += (size_t)BT_ * 2 * 4;         // 128 KB
    float* part   = (float*)p;  p += (size_t)BT_ * NB * 5 * 4;    // 5.2 MB
    float* gamma  = (float*)p;  p += (size_t)BT_ * 4;             // 64 KB

    hipFuncSetAttribute((const void*)gemm8<0, 1>,
                        hipFuncAttributeMaxDynamicSharedMemorySize, 65536);
    hipFuncSetAttribute((const void*)gemm8<2, 0>,
                        hipFuncAttributeMaxDynamicSharedMemorySize, 65536);
    hipFuncSetAttribute((const void*)gemm8<3, 0>,
                        hipFuncAttributeMaxDynamicSharedMemorySize, 65536);

    k_cvt_wk3<<<(HID * ED) / 256, 256, 0, stream>>>(Wk, Wk3);
    k_packWo<<<(HID * HID) / 256, 256, 0, stream>>>(Wo, WoP);
    k_packWv<<<(HID * ED) / 256, 256, 0, stream>>>(Wv, WvP);
    k_gather<<<BT_, 256, 0, stream>>>(hashes, offs, emb, E);
    k_conv<<<BT_, 256, 0, stream>>>(E, conv_w, lncg, lncb, A3);
    k_xstat<<<BT_, 256, 0, stream>>>(x, xs);

    // W2 = Wo @ Wv split-precision, K-split 8 x 768 -> f32 slabs (over dead E).
    // M=2048 (16 m-tiles) x N=256 (2 n-tiles) = 32 blocks x 8 K-splits.
    gemm8<0, 1><<<dim3((HID / 128) * (ED / 128), KSP), 256, 65536, stream>>>(
        WoP, KW, WvP, KW, nullptr, W2part, HID, ED, KW / KSP,
        nullptr, nullptr, nullptr, nullptr, nullptr, nullptr, nullptr);
    k_w2pack<<<(HID * ED) / 256, 256, 0, stream>>>(W2part, W23);

    const dim3 grid((BT_ / 128) * (HID / 128));   // 2048 blocks = 128x16 tiles
    // key partials: A3 @ Wk3^T (K=768), gamma reduction fused in epilogue
    gemm8<2, 0><<<grid, 256, 65536, stream>>>(
        A3, K3, Wk3, K3, nullptr, nullptr, BT_, HID, K3,
        x, xs, lnqg, lnqb, lnkg, lnkb, part);
    k_gamma2<<<BT_ / 256, 256, 0, stream>>>(part, gamma);
    // out = gamma * (A3 @ W23^T)  (K=768) -> d_out f32
    gemm8<3, 0><<<grid, 256, 65536, stream>>>(
        A3, K3, W23, K3, gamma, d_out, BT_, HID, K3,
        nullptr, nullptr, nullptr, nullptr, nullptr, nullptr, nullptr);
}